// Round 1
// baseline (45.455 us; speedup 1.0000x reference)
//
#include <hip/hip_runtime.h>
#include <math.h>

// Problem constants (match reference)
#define BB 32
#define TT 50
#define HH 76
#define WW 76
#define NA 5
#define NC 20
#define KK 25           // 5 + NC
#define HW (HH*WW)      // 5776
#define BT (BB*TT)      // 1600

// ws layout (floats):
//   tb[12][BT]  : per-target table            (12*1600 = 19200 floats)
//   partial[..] : per-block partial sums      (grid2x * BB floats)
#define TB_FLOATS (12*BT)

// tb field indices
#define F_CELL  0   // int: (cj*WW+ci)*NA + max_n   (b folded out; k2 blocks are per-b)
#define F_X1    1
#define F_X2    2
#define F_Y1    3
#define F_Y2    4
#define F_A06   5   // 0.6 * (bw*bh)
#define F_TX    6
#define F_TY    7
#define F_TW    8
#define F_TH    9
#define F_SC   10
#define F_CLS  11   // int: class id

__global__ __launch_bounds__(256) void prep_kernel(
    const float* __restrict__ out, const float* __restrict__ tgt,
    const float* __restrict__ pri, float* __restrict__ tb)
{
    int i = blockIdx.x * blockDim.x + threadIdx.x;
    if (i >= BT) return;
    int b = i / TT;
    const float* tp = tgt + (size_t)i * 5;
    float cls = tp[0], bx = tp[1], by = tp[2], bw = tp[3], bh = tp[4];
    int ci = (int)floorf(bx * WW);
    int cj = (int)floorf(by * HH);

    // anchor assignment: IoU of (0,0,bw,bh) vs (0,0,pw_cell,ph_cell), first-argmax
    const float* ob = out + (size_t)b * KK * NA * HW + (size_t)cj * WW + ci;
    float best = -1.0f; int bn = 0;
    #pragma unroll
    for (int n = 0; n < NA; ++n) {
        float o2 = ob[(size_t)(n*KK + 2) * HW];
        float o3 = ob[(size_t)(n*KK + 3) * HW];
        float pw = pri[2*n]   * __expf(o2) * (1.0f/WW);
        float ph = pri[2*n+1] * __expf(o3) * (1.0f/HH);
        float inter = fminf(bw, pw) * fminf(bh, ph);
        float iou = inter / (bw*bh + pw*ph - inter);
        if (iou > best) { best = iou; bn = n; }
    }

    float tx = bx * WW - (float)ci;
    float ty = by * HH - (float)cj;
    float tw = __logf(bw * WW / pri[2*bn]);
    float th = __logf(bh * HH / pri[2*bn+1]);
    if (tw != tw) tw = 0.0f;  // NaN guard (matches reference)
    if (th != th) th = 0.0f;
    float scale = 2.0f - bw * bh;

    tb[F_CELL*BT + i] = __int_as_float((cj*WW + ci)*NA + bn);
    tb[F_X1*BT + i] = bx - 0.5f*bw;
    tb[F_X2*BT + i] = bx + 0.5f*bw;
    tb[F_Y1*BT + i] = by - 0.5f*bh;
    tb[F_Y2*BT + i] = by + 0.5f*bh;
    tb[F_A06*BT + i] = 0.6f * (bw*bh);
    tb[F_TX*BT + i] = tx;
    tb[F_TY*BT + i] = ty;
    tb[F_TW*BT + i] = tw;
    tb[F_TH*BT + i] = th;
    tb[F_SC*BT + i] = scale;
    tb[F_CLS*BT + i] = __int_as_float((int)floorf(cls));
}

__global__ __launch_bounds__(256) void main_kernel(
    const float* __restrict__ out, const float* __restrict__ pri,
    const float* __restrict__ tb, float* __restrict__ partial)
{
    __shared__ float st[12][TT];
    const int b = blockIdx.y;
    const int tid = threadIdx.x;

    for (int j = tid; j < 12*TT; j += 256) {
        int f = j / TT, t = j - f*TT;
        st[f][t] = tb[f*BT + b*TT + t];
    }
    __syncthreads();

    float mysum = 0.0f;
    int idx = blockIdx.x * 256 + tid;
    if (idx < NA*HW) {
        int n = idx / HW;
        int rem = idx - n*HW;
        int h = rem / WW;
        int w = rem - h*WW;

        const float* op = out + ((size_t)b*KK*NA + (size_t)n*KK) * HW + rem;
        float o0 = op[0];
        float o1 = op[HW];
        float o2 = op[2*HW];
        float o3 = op[3*HW];
        float o4 = op[4*HW];

        float px = ((float)w + o0) * (1.0f/WW);
        float py = ((float)h + o1) * (1.0f/HH);
        float pw = pri[2*n]   * __expf(o2) * (1.0f/WW);
        float ph = pri[2*n+1] * __expf(o3) * (1.0f/HH);
        float ax1 = px - 0.5f*pw, ax2 = px + 0.5f*pw;
        float ay1 = py - 0.5f*ph, ay2 = py + 0.5f*ph;
        float pb06 = 0.6f * (pw*ph);
        int mycell = (h*WW + w)*NA + n;

        int ot = -1;
        bool iou_hit = false;
        #pragma unroll 5
        for (int t = 0; t < TT; ++t) {
            float iw = fminf(ax2, st[F_X2][t]) - fmaxf(ax1, st[F_X1][t]);
            float ih = fminf(ay2, st[F_Y2][t]) - fmaxf(ay1, st[F_Y1][t]);
            iw = fmaxf(iw, 0.0f);
            ih = fmaxf(ih, 0.0f);
            float inter = iw * ih;
            // inter/(pa+ba-inter) > 0.6  <=>  1.6*inter > 0.6*pa + 0.6*ba  (union>0 always)
            iou_hit = iou_hit | (1.6f*inter > pb06 + st[F_A06][t]);
            if (__float_as_int(st[F_CELL][t]) == mycell) ot = t;  // later t wins
        }

        if (ot >= 0) {
            float sc = st[F_SC][ot];
            float d0 = sc * (st[F_TX][ot] - o0);
            float d1 = sc * (st[F_TY][ot] - o1);
            float d2 = sc * (st[F_TW][ot] - o2);
            float d3 = sc * (st[F_TH][ot] - o3);
            float dob = 5.0f * (1.0f - o4);
            mysum = d0*d0 + d1*d1 + d2*d2 + d3*d3 + dob*dob;
            int tc = __float_as_int(st[F_CLS][ot]);
            #pragma unroll
            for (int c = 0; c < NC; ++c) {
                float oc = op[(size_t)(5 + c) * HW];
                float d = ((c == tc) ? 1.0f : 0.0f) - oc;
                mysum += d * d;
            }
        } else if (!iou_hit) {
            mysum = o4 * o4;  // noobj penalty
        }
    }

    // deterministic block reduction: wave shuffle + LDS across 4 waves
    #pragma unroll
    for (int off = 32; off > 0; off >>= 1)
        mysum += __shfl_down(mysum, off, 64);
    __shared__ float swave[4];
    if ((tid & 63) == 0) swave[tid >> 6] = mysum;
    __syncthreads();
    if (tid == 0)
        partial[blockIdx.y * gridDim.x + blockIdx.x] =
            swave[0] + swave[1] + swave[2] + swave[3];
}

__global__ __launch_bounds__(256) void reduce_kernel(
    const float* __restrict__ partial, int n, float* __restrict__ outp)
{
    int tid = threadIdx.x;
    float s = 0.0f;
    for (int i = tid; i < n; i += 256) s += partial[i];
    #pragma unroll
    for (int off = 32; off > 0; off >>= 1)
        s += __shfl_down(s, off, 64);
    __shared__ float swave[4];
    if ((tid & 63) == 0) swave[tid >> 6] = s;
    __syncthreads();
    if (tid == 0) {
        float total = swave[0] + swave[1] + swave[2] + swave[3];
        float r = sqrtf(total);
        outp[0] = r * r;   // mirror reference: sqrt(sum)^2
    }
}

extern "C" void kernel_launch(void* const* d_in, const int* in_sizes, int n_in,
                              void* d_out, int out_size, void* d_ws, size_t ws_size,
                              hipStream_t stream) {
    const float* output = (const float*)d_in[0];
    const float* target = (const float*)d_in[1];
    const float* priors = (const float*)d_in[2];
    float* ws = (float*)d_ws;

    float* tb = ws;                       // 12*BT floats
    float* partial = ws + TB_FLOATS;      // grid2x*BB floats

    const int grid2x = (NA*HW + 255) / 256;   // 113

    prep_kernel<<<(BT + 255)/256, 256, 0, stream>>>(output, target, priors, tb);
    main_kernel<<<dim3(grid2x, BB), 256, 0, stream>>>(output, priors, tb, partial);
    reduce_kernel<<<1, 256, 0, stream>>>(partial, grid2x * BB, (float*)d_out);
}

// Round 2
// 39.332 us; speedup vs baseline: 1.1557x; 1.1557x over previous
//
#include <hip/hip_runtime.h>
#include <math.h>

// Problem constants (match reference)
#define BB 32
#define TT 50
#define HH 76
#define WW 76
#define NA 5
#define NC 20
#define KK 25           // 5 + NC
#define HW (HH*WW)      // 5776
#define BT (BB*TT)      // 1600

// ws layout (floats):
//   tb[BB][12][TT] : per-target table, per-batch contiguous (12*50*4 = 2400 B each)
//   partial[..]    : per-block partial sums (grid2x * BB floats)
#define TB_FLOATS (BB*12*TT)

// tb field indices (within a batch's [12][TT] block)
#define F_CELL  0   // int: (cj*WW+ci)*NA + max_n
#define F_X1    1
#define F_X2    2
#define F_Y1    3
#define F_Y2    4
#define F_A375  5   // 0.375 * (bw*bh)   -- pre-scaled IoU threshold term
#define F_TX    6
#define F_TY    7
#define F_TW    8
#define F_TH    9
#define F_SC   10
#define F_CLS  11   // int: class id

__global__ __launch_bounds__(256) void prep_kernel(
    const float* __restrict__ out, const float* __restrict__ tgt,
    const float* __restrict__ pri, float* __restrict__ tb)
{
    int i = blockIdx.x * blockDim.x + threadIdx.x;
    if (i >= BT) return;
    int b = i / TT;
    int t = i - b * TT;
    const float* tp = tgt + (size_t)i * 5;
    float cls = tp[0], bx = tp[1], by = tp[2], bw = tp[3], bh = tp[4];
    int ci = (int)floorf(bx * WW);
    int cj = (int)floorf(by * HH);

    // anchor assignment: IoU of (0,0,bw,bh) vs (0,0,pw_cell,ph_cell), first-argmax
    const float* ob = out + (size_t)b * KK * NA * HW + (size_t)cj * WW + ci;
    float best = -1.0f; int bn = 0;
    #pragma unroll
    for (int n = 0; n < NA; ++n) {
        float o2 = ob[(size_t)(n*KK + 2) * HW];
        float o3 = ob[(size_t)(n*KK + 3) * HW];
        float pw = pri[2*n]   * __expf(o2) * (1.0f/WW);
        float ph = pri[2*n+1] * __expf(o3) * (1.0f/HH);
        float inter = fminf(bw, pw) * fminf(bh, ph);
        float iou = inter / (bw*bh + pw*ph - inter);
        if (iou > best) { best = iou; bn = n; }
    }

    float tx = bx * WW - (float)ci;
    float ty = by * HH - (float)cj;
    float tw = __logf(bw * WW / pri[2*bn]);
    float th = __logf(bh * HH / pri[2*bn+1]);
    if (tw != tw) tw = 0.0f;  // NaN guard (matches reference)
    if (th != th) th = 0.0f;
    float scale = 2.0f - bw * bh;

    float* tbb = tb + (size_t)b * 12 * TT;
    tbb[F_CELL*TT + t] = __int_as_float((cj*WW + ci)*NA + bn);
    tbb[F_X1*TT + t] = bx - 0.5f*bw;
    tbb[F_X2*TT + t] = bx + 0.5f*bw;
    tbb[F_Y1*TT + t] = by - 0.5f*bh;
    tbb[F_Y2*TT + t] = by + 0.5f*bh;
    tbb[F_A375*TT + t] = 0.375f * (bw*bh);
    tbb[F_TX*TT + t] = tx;
    tbb[F_TY*TT + t] = ty;
    tbb[F_TW*TT + t] = tw;
    tbb[F_TH*TT + t] = th;
    tbb[F_SC*TT + t] = scale;
    tbb[F_CLS*TT + t] = __int_as_float((int)floorf(cls));
}

__global__ __launch_bounds__(256) void main_kernel(
    const float* __restrict__ out, const float* __restrict__ pri,
    const float* __restrict__ tb, float* __restrict__ partial)
{
    const int b = blockIdx.y;
    const int tid = threadIdx.x;

    // block-uniform target-table pointers -> scalar loads (SGPR operands)
    const float* __restrict__ tbb = tb + (size_t)b * 12 * TT;
    const float* __restrict__ s_x1 = tbb + F_X1*TT;
    const float* __restrict__ s_x2 = tbb + F_X2*TT;
    const float* __restrict__ s_y1 = tbb + F_Y1*TT;
    const float* __restrict__ s_y2 = tbb + F_Y2*TT;
    const float* __restrict__ s_a  = tbb + F_A375*TT;
    const float* __restrict__ s_cl = tbb + F_CELL*TT;

    float mysum = 0.0f;
    int idx = blockIdx.x * 256 + tid;
    if (idx < NA*HW) {
        int n = idx / HW;
        int rem = idx - n*HW;
        int h = rem / WW;
        int w = rem - h*WW;

        const float* op = out + ((size_t)b*KK*NA + (size_t)n*KK) * HW + rem;
        float o0 = op[0];
        float o1 = op[HW];
        float o2 = op[2*HW];
        float o3 = op[3*HW];
        float o4 = op[4*HW];

        float px = ((float)w + o0) * (1.0f/WW);
        float py = ((float)h + o1) * (1.0f/HH);
        float pw = pri[2*n]   * __expf(o2) * (1.0f/WW);
        float ph = pri[2*n+1] * __expf(o3) * (1.0f/HH);
        float ax1 = px - 0.5f*pw, ax2 = px + 0.5f*pw;
        float ay1 = py - 0.5f*ph, ay2 = py + 0.5f*ph;
        float pb = 0.375f * (pw*ph);
        int mycell = (h*WW + w)*NA + n;

        int ot = -1;
        bool iou_hit = false;
        #pragma unroll
        for (int t = 0; t < TT; ++t) {
            float iw = fminf(ax2, s_x2[t]) - fmaxf(ax1, s_x1[t]);
            float ih = fminf(ay2, s_y2[t]) - fmaxf(ay1, s_y1[t]);
            iw = fmaxf(iw, 0.0f);
            ih = fmaxf(ih, 0.0f);
            float inter = iw * ih;
            // IoU > 0.6  <=>  inter > 0.375*pa + 0.375*ba
            iou_hit = iou_hit | (inter > pb + s_a[t]);
            if (__float_as_int(s_cl[t]) == mycell) ot = t;  // later t wins
        }

        if (ot >= 0) {
            float sc = tbb[F_SC*TT + ot];
            float d0 = sc * (tbb[F_TX*TT + ot] - o0);
            float d1 = sc * (tbb[F_TY*TT + ot] - o1);
            float d2 = sc * (tbb[F_TW*TT + ot] - o2);
            float d3 = sc * (tbb[F_TH*TT + ot] - o3);
            float dob = 5.0f * (1.0f - o4);
            mysum = d0*d0 + d1*d1 + d2*d2 + d3*d3 + dob*dob;
            int tc = __float_as_int(tbb[F_CLS*TT + ot]);
            #pragma unroll
            for (int c = 0; c < NC; ++c) {
                float oc = op[(size_t)(5 + c) * HW];
                float d = ((c == tc) ? 1.0f : 0.0f) - oc;
                mysum += d * d;
            }
        } else if (!iou_hit) {
            mysum = o4 * o4;  // noobj penalty
        }
    }

    // deterministic block reduction: wave shuffle + LDS across 4 waves
    #pragma unroll
    for (int off = 32; off > 0; off >>= 1)
        mysum += __shfl_down(mysum, off, 64);
    __shared__ float swave[4];
    if ((tid & 63) == 0) swave[tid >> 6] = mysum;
    __syncthreads();
    if (tid == 0)
        partial[blockIdx.y * gridDim.x + blockIdx.x] =
            swave[0] + swave[1] + swave[2] + swave[3];
}

__global__ __launch_bounds__(256) void reduce_kernel(
    const float* __restrict__ partial, int n, float* __restrict__ outp)
{
    int tid = threadIdx.x;
    float s = 0.0f;
    for (int i = tid; i < n; i += 256) s += partial[i];
    #pragma unroll
    for (int off = 32; off > 0; off >>= 1)
        s += __shfl_down(s, off, 64);
    __shared__ float swave[4];
    if ((tid & 63) == 0) swave[tid >> 6] = s;
    __syncthreads();
    if (tid == 0) {
        float total = swave[0] + swave[1] + swave[2] + swave[3];
        float r = sqrtf(total);
        outp[0] = r * r;   // mirror reference: sqrt(sum)^2
    }
}

extern "C" void kernel_launch(void* const* d_in, const int* in_sizes, int n_in,
                              void* d_out, int out_size, void* d_ws, size_t ws_size,
                              hipStream_t stream) {
    const float* output = (const float*)d_in[0];
    const float* target = (const float*)d_in[1];
    const float* priors = (const float*)d_in[2];
    float* ws = (float*)d_ws;

    float* tb = ws;                       // BB*12*TT floats
    float* partial = ws + TB_FLOATS;      // grid2x*BB floats

    const int grid2x = (NA*HW + 255) / 256;   // 113

    prep_kernel<<<(BT + 255)/256, 256, 0, stream>>>(output, target, priors, tb);
    main_kernel<<<dim3(grid2x, BB), 256, 0, stream>>>(output, priors, tb, partial);
    reduce_kernel<<<1, 256, 0, stream>>>(partial, grid2x * BB, (float*)d_out);
}

// Round 3
// 33.482 us; speedup vs baseline: 1.3576x; 1.1747x over previous
//
#include <hip/hip_runtime.h>
#include <math.h>

// Problem constants (match reference)
#define BB 32
#define TT 50
#define HH 76
#define WW 76
#define NA 5
#define NC 20
#define KK 25           // 5 + NC
#define HW (HH*WW)      // 5776
#define BT (BB*TT)      // 1600
#define CELLS (NA*HW)   // 28880
#define CPT 4           // cells per thread in main
#define TPB_CELLS (CELLS/CPT)       // 7220
#define MBX ((TPB_CELLS + 255)/256) // 29 main blocks per batch
#define GX (MBX + 1)    // +1 owner block per batch -> 30

// ws layout (floats): tb[BB][12][TT], partial[BB*GX]
#define TB_FLOATS (BB*12*TT)

// tb field indices (within a batch's [12][TT] block)
#define F_CELL  0   // int bits: (cj*WW+ci)*NA + max_n
#define F_X1    1
#define F_X2    2
#define F_Y1    3
#define F_Y2    4
#define F_NA    5   // -0.375 * (bw*bh)
#define F_TX    6
#define F_TY    7
#define F_TW    8
#define F_TH    9
#define F_SC   10
#define F_CLS  11   // int bits: class id

#define RDLANE(v, t) __uint_as_float((unsigned)__builtin_amdgcn_readlane((int)__float_as_uint(v), (t)))

// identical source for main & owner so the noobj subtraction cancels exactly
#define IOU_STEP(AX1, AX2, AY1, AY2, NPB, ACC) do {          \
    float iw_ = fminf(AX2, sx2) - fmaxf(AX1, sx1);           \
    float ih_ = fminf(AY2, sy2) - fmaxf(AY1, sy1);           \
    iw_ = fmaxf(iw_, 0.0f);  ih_ = fmaxf(ih_, 0.0f);         \
    float ns_ = (NPB) + sna;                                 \
    (ACC) = fmaxf((ACC), fmaf(iw_, ih_, ns_)); } while (0)

__global__ __launch_bounds__(256) void prep_kernel(
    const float* __restrict__ out, const float* __restrict__ tgt,
    const float* __restrict__ pri, float* __restrict__ tb)
{
    int i = blockIdx.x * blockDim.x + threadIdx.x;
    if (i >= BT) return;
    int b = i / TT;
    int t = i - b * TT;
    const float* tp = tgt + (size_t)i * 5;
    float cls = tp[0], bx = tp[1], by = tp[2], bw = tp[3], bh = tp[4];
    int ci = (int)floorf(bx * WW);
    int cj = (int)floorf(by * HH);

    // anchor assignment: IoU of (0,0,bw,bh) vs (0,0,pw_cell,ph_cell), first-argmax
    const float* ob = out + (size_t)b * KK * NA * HW + (size_t)cj * WW + ci;
    float best = -1.0f; int bn = 0;
    #pragma unroll
    for (int n = 0; n < NA; ++n) {
        float o2 = ob[(size_t)(n*KK + 2) * HW];
        float o3 = ob[(size_t)(n*KK + 3) * HW];
        float pw = pri[2*n]   * __expf(o2) * (1.0f/WW);
        float ph = pri[2*n+1] * __expf(o3) * (1.0f/HH);
        float inter = fminf(bw, pw) * fminf(bh, ph);
        float iou = inter / (bw*bh + pw*ph - inter);
        if (iou > best) { best = iou; bn = n; }
    }

    float tx = bx * WW - (float)ci;
    float ty = by * HH - (float)cj;
    float tw = __logf(bw * WW / pri[2*bn]);
    float th = __logf(bh * HH / pri[2*bn+1]);
    if (tw != tw) tw = 0.0f;  // NaN guard (matches reference)
    if (th != th) th = 0.0f;
    float scale = 2.0f - bw * bh;

    float* tbb = tb + (size_t)b * 12 * TT;
    tbb[F_CELL*TT + t] = __int_as_float((cj*WW + ci)*NA + bn);
    tbb[F_X1*TT + t] = bx - 0.5f*bw;
    tbb[F_X2*TT + t] = bx + 0.5f*bw;
    tbb[F_Y1*TT + t] = by - 0.5f*bh;
    tbb[F_Y2*TT + t] = by + 0.5f*bh;
    tbb[F_NA*TT + t] = -0.375f * (bw*bh);
    tbb[F_TX*TT + t] = tx;
    tbb[F_TY*TT + t] = ty;
    tbb[F_TW*TT + t] = tw;
    tbb[F_TH*TT + t] = th;
    tbb[F_SC*TT + t] = scale;
    tbb[F_CLS*TT + t] = __int_as_float((int)floorf(cls));
}

__global__ __launch_bounds__(256) void main_kernel(
    const float* __restrict__ out, const float* __restrict__ pri,
    const float* __restrict__ tb, float* __restrict__ partial)
{
    const int b = blockIdx.y;
    const int tid = threadIdx.x;
    const float* __restrict__ tbb = tb + (size_t)b * 12 * TT;
    const int lane = tid & 63;
    const int tl = (lane < TT) ? lane : (TT - 1);

    // wave-held target table: lane t holds target t's fields
    float vx1 = tbb[F_X1*TT + tl];
    float vx2 = tbb[F_X2*TT + tl];
    float vy1 = tbb[F_Y1*TT + tl];
    float vy2 = tbb[F_Y2*TT + tl];
    float vna = tbb[F_NA*TT + tl];

    float mysum = 0.0f;

    if (blockIdx.x < MBX) {
        // ---- main path: 4 cells per thread, noobj/iou only ----
        int k = blockIdx.x * 256 + tid;
        float valid = (k < TPB_CELLS) ? 1.0f : 0.0f;
        int kc = (k < TPB_CELLS) ? k : (TPB_CELLS - 1);

        float ax1[CPT], ax2[CPT], ay1[CPT], ay2[CPT], npb[CPT], o4v[CPT];
        #pragma unroll
        for (int j = 0; j < CPT; ++j) {
            int cell = kc + j * TPB_CELLS;   // flat (n*HW + rem) enumeration
            int n = cell / HW;
            int rem = cell - n * HW;
            int h = rem / WW;
            int w = rem - h * WW;
            const float* op = out + ((size_t)(b*KK*NA + n*KK)) * HW + rem;
            float o0 = op[0];
            float o1 = op[HW];
            float o2 = op[2*HW];
            float o3 = op[3*HW];
            o4v[j] = op[4*HW];
            float px = ((float)w + o0) * (1.0f/WW);
            float py = ((float)h + o1) * (1.0f/HH);
            float pw = pri[2*n]   * __expf(o2) * (1.0f/WW);
            float ph = pri[2*n+1] * __expf(o3) * (1.0f/HH);
            ax1[j] = px - 0.5f*pw;  ax2[j] = px + 0.5f*pw;
            ay1[j] = py - 0.5f*ph;  ay2[j] = py + 0.5f*ph;
            npb[j] = -0.375f * (pw*ph);
        }

        float acc[CPT];
        #pragma unroll
        for (int j = 0; j < CPT; ++j) acc[j] = -1.0f;

        #pragma unroll 10
        for (int t = 0; t < TT; ++t) {
            float sx1 = RDLANE(vx1, t);
            float sx2 = RDLANE(vx2, t);
            float sy1 = RDLANE(vy1, t);
            float sy2 = RDLANE(vy2, t);
            float sna = RDLANE(vna, t);
            IOU_STEP(ax1[0], ax2[0], ay1[0], ay2[0], npb[0], acc[0]);
            IOU_STEP(ax1[1], ax2[1], ay1[1], ay2[1], npb[1], acc[1]);
            IOU_STEP(ax1[2], ax2[2], ay1[2], ay2[2], npb[2], acc[2]);
            IOU_STEP(ax1[3], ax2[3], ay1[3], ay2[3], npb[3], acc[3]);
        }

        #pragma unroll
        for (int j = 0; j < CPT; ++j)
            mysum += (acc[j] > 0.0f) ? 0.0f : o4v[j] * o4v[j];
        mysum *= valid;
    } else {
        // ---- owner block: one per batch; threads 0..TT-1 = targets ----
        float vcf = tbb[F_CELL*TT + tl];
        if (tid < TT) {
            int t = tid;
            int mycell = __float_as_int(vcf);   // lane t holds row t
            bool dead = false;
            #pragma unroll 10
            for (int t2 = 0; t2 < TT; ++t2) {
                int c2 = __builtin_amdgcn_readlane((int)__float_as_uint(vcf), t2);
                dead = dead || (c2 == mycell && t2 > t);
            }
            if (!dead) {
                int n = mycell % NA;
                int rem = mycell / NA;
                int h = rem / WW;
                int w = rem - h * WW;
                const float* op = out + ((size_t)(b*KK*NA + n*KK)) * HW + rem;
                float o0 = op[0];
                float o1 = op[HW];
                float o2 = op[2*HW];
                float o3 = op[3*HW];
                float o4 = op[4*HW];

                float sc = tbb[F_SC*TT + t];
                float d0 = sc * (tbb[F_TX*TT + t] - o0);
                float d1 = sc * (tbb[F_TY*TT + t] - o1);
                float d2 = sc * (tbb[F_TW*TT + t] - o2);
                float d3 = sc * (tbb[F_TH*TT + t] - o3);
                float dob = 5.0f * (1.0f - o4);
                float s = d0*d0 + d1*d1 + d2*d2 + d3*d3 + dob*dob;
                int tc = __float_as_int(tbb[F_CLS*TT + t]);
                #pragma unroll
                for (int c = 0; c < NC; ++c) {
                    float oc = op[(size_t)(5 + c) * HW];
                    float d = ((c == tc) ? 1.0f : 0.0f) - oc;
                    s += d * d;
                }

                // recompute this cell's iou-hit with the identical chain,
                // subtract the noobj term main_kernel added for this cell
                float px = ((float)w + o0) * (1.0f/WW);
                float py = ((float)h + o1) * (1.0f/HH);
                float pw = pri[2*n]   * __expf(o2) * (1.0f/WW);
                float ph = pri[2*n+1] * __expf(o3) * (1.0f/HH);
                float ax1 = px - 0.5f*pw, ax2 = px + 0.5f*pw;
                float ay1 = py - 0.5f*ph, ay2 = py + 0.5f*ph;
                float npb = -0.375f * (pw*ph);
                float acc = -1.0f;
                #pragma unroll 10
                for (int t2 = 0; t2 < TT; ++t2) {
                    float sx1 = RDLANE(vx1, t2);
                    float sx2 = RDLANE(vx2, t2);
                    float sy1 = RDLANE(vy1, t2);
                    float sy2 = RDLANE(vy2, t2);
                    float sna = RDLANE(vna, t2);
                    IOU_STEP(ax1, ax2, ay1, ay2, npb, acc);
                }
                s -= (acc > 0.0f) ? 0.0f : o4 * o4;
                mysum = s;
            }
        }
    }

    // deterministic block reduction: wave shuffle + LDS across 4 waves
    #pragma unroll
    for (int off = 32; off > 0; off >>= 1)
        mysum += __shfl_down(mysum, off, 64);
    __shared__ float swave[4];
    if ((tid & 63) == 0) swave[tid >> 6] = mysum;
    __syncthreads();
    if (tid == 0)
        partial[blockIdx.y * gridDim.x + blockIdx.x] =
            swave[0] + swave[1] + swave[2] + swave[3];
}

__global__ __launch_bounds__(256) void reduce_kernel(
    const float* __restrict__ partial, int n, float* __restrict__ outp)
{
    int tid = threadIdx.x;
    float s = 0.0f;
    for (int i = tid; i < n; i += 256) s += partial[i];
    #pragma unroll
    for (int off = 32; off > 0; off >>= 1)
        s += __shfl_down(s, off, 64);
    __shared__ float swave[4];
    if ((tid & 63) == 0) swave[tid >> 6] = s;
    __syncthreads();
    if (tid == 0) {
        float total = swave[0] + swave[1] + swave[2] + swave[3];
        float r = sqrtf(total);
        outp[0] = r * r;   // mirror reference: sqrt(sum)^2
    }
}

extern "C" void kernel_launch(void* const* d_in, const int* in_sizes, int n_in,
                              void* d_out, int out_size, void* d_ws, size_t ws_size,
                              hipStream_t stream) {
    const float* output = (const float*)d_in[0];
    const float* target = (const float*)d_in[1];
    const float* priors = (const float*)d_in[2];
    float* ws = (float*)d_ws;

    float* tb = ws;                       // BB*12*TT floats
    float* partial = ws + TB_FLOATS;      // BB*GX floats

    prep_kernel<<<(BT + 255)/256, 256, 0, stream>>>(output, target, priors, tb);
    main_kernel<<<dim3(GX, BB), 256, 0, stream>>>(output, priors, tb, partial);
    reduce_kernel<<<1, 256, 0, stream>>>(partial, GX * BB, (float*)d_out);
}

// Round 5
// 28.646 us; speedup vs baseline: 1.5868x; 1.1688x over previous
//
#include <hip/hip_runtime.h>
#include <math.h>

// Problem constants (match reference)
#define BB 32
#define TT 50
#define HH 76
#define WW 76
#define NA 5
#define NC 20
#define KK 25           // 5 + NC
#define HW (HH*WW)      // 5776
#define CPT 5           // cells per thread: all anchors of one spatial pos
#define TPB_CELLS HW    // 5776 threads per batch
#define MBX ((TPB_CELLS + 255)/256) // 23 main blocks per batch
#define GX (MBX + 1)    // +1 owner block per batch -> 24

#define RDLANE(v, t) __uint_as_float((unsigned)__builtin_amdgcn_readlane((int)__float_as_uint(v), (t)))

// R3-proven clamped form: hit <=> acc > 0 <=> inter > 0.375*(pa+ba) <=> IoU > 0.6
// identical macro + iteration order in main & owner so the noobj subtraction cancels exactly
#define IOU_STEP(AX1, AX2, AY1, AY2, NPB, ACC) do {          \
    float iw_ = fminf(AX2, sx2) - fmaxf(AX1, sx1);           \
    float ih_ = fminf(AY2, sy2) - fmaxf(AY1, sy1);           \
    iw_ = fmaxf(iw_, 0.0f);  ih_ = fmaxf(ih_, 0.0f);         \
    float ns_ = (NPB) + sna;                                 \
    (ACC) = fmaxf((ACC), fmaf(iw_, ih_, ns_)); } while (0)

__global__ __launch_bounds__(256) void fused_kernel(
    const float* __restrict__ out, const float* __restrict__ tgt,
    const float* __restrict__ pri, float* __restrict__ partial)
{
    const int b = blockIdx.y;
    const int tid = threadIdx.x;
    const int lane = tid & 63;
    const int tl = (lane < TT) ? lane : (TT - 1);

    // wave-held target table, built under FULL exec (uniform control flow):
    // lane t holds target t's box corners and -0.375*area
    const float* tp = tgt + ((size_t)b * TT + tl) * 5;
    float bx = tp[1], by = tp[2], bw = tp[3], bh = tp[4];
    float vx1 = fmaf(-0.5f, bw, bx);
    float vx2 = fmaf( 0.5f, bw, bx);
    float vy1 = fmaf(-0.5f, bh, by);
    float vy2 = fmaf( 0.5f, bh, by);
    float vna = -0.375f * (bw * bh);

    float mysum = 0.0f;

    if (blockIdx.x < MBX) {
        // ---- main path: 5 cells (all anchors of one spatial pos) per thread ----
        int k = blockIdx.x * 256 + tid;
        float valid = (k < TPB_CELLS) ? 1.0f : 0.0f;
        int rem = (k < TPB_CELLS) ? k : (TPB_CELLS - 1);
        int h = rem / WW;
        int w = rem - h * WW;

        const float* op0 = out + (size_t)b * KK * NA * HW + rem;
        float ax1[CPT], ax2[CPT], ay1[CPT], ay2[CPT], npb[CPT], o4v[CPT];
        #pragma unroll
        for (int n = 0; n < NA; ++n) {
            const float* op = op0 + (size_t)(n * KK) * HW;
            float o0 = op[0];
            float o1 = op[HW];
            float o2 = op[2*HW];
            float o3 = op[3*HW];
            o4v[n] = op[4*HW];
            float px = ((float)w + o0) * (1.0f/WW);
            float py = ((float)h + o1) * (1.0f/HH);
            float pw = pri[2*n]   * __expf(o2) * (1.0f/WW);
            float ph = pri[2*n+1] * __expf(o3) * (1.0f/HH);
            ax1[n] = fmaf(-0.5f, pw, px);  ax2[n] = fmaf(0.5f, pw, px);
            ay1[n] = fmaf(-0.5f, ph, py);  ay2[n] = fmaf(0.5f, ph, py);
            npb[n] = -0.375f * (pw * ph);
        }

        float acc[CPT];
        #pragma unroll
        for (int j = 0; j < CPT; ++j) acc[j] = -1.0f;

        #pragma unroll 10
        for (int t = 0; t < TT; ++t) {
            float sx1 = RDLANE(vx1, t);
            float sx2 = RDLANE(vx2, t);
            float sy1 = RDLANE(vy1, t);
            float sy2 = RDLANE(vy2, t);
            float sna = RDLANE(vna, t);
            IOU_STEP(ax1[0], ax2[0], ay1[0], ay2[0], npb[0], acc[0]);
            IOU_STEP(ax1[1], ax2[1], ay1[1], ay2[1], npb[1], acc[1]);
            IOU_STEP(ax1[2], ax2[2], ay1[2], ay2[2], npb[2], acc[2]);
            IOU_STEP(ax1[3], ax2[3], ay1[3], ay2[3], npb[3], acc[3]);
            IOU_STEP(ax1[4], ax2[4], ay1[4], ay2[4], npb[4], acc[4]);
        }

        float s = 0.0f;
        #pragma unroll
        for (int j = 0; j < CPT; ++j)
            s += (acc[j] > 0.0f) ? 0.0f : o4v[j] * o4v[j];
        mysum = s * valid;
    } else {
        // ---- owner path: FULLY UNIFORM across the block; liveness applied as
        // a multiply at the end. Lanes >= TT and waves 1..3 compute masked
        // duplicates of target TT-1 on valid addresses (all values finite). ----
        float cls = tp[0];
        int ci = (int)floorf(bx * WW);
        int cj = (int)floorf(by * HH);

        // anchor assignment: IoU of (0,0,bw,bh) vs (0,0,pw_cell,ph_cell), first-argmax
        const float* ob = out + (size_t)b * KK * NA * HW + (size_t)cj * WW + ci;
        float best = -1.0f; int bn = 0;
        #pragma unroll
        for (int n = 0; n < NA; ++n) {
            float e2 = ob[(size_t)(n*KK + 2) * HW];
            float e3 = ob[(size_t)(n*KK + 3) * HW];
            float pw = pri[2*n]   * __expf(e2) * (1.0f/WW);
            float ph = pri[2*n+1] * __expf(e3) * (1.0f/HH);
            float inter = fminf(bw, pw) * fminf(bh, ph);
            float iou = inter / (bw*bh + pw*ph - inter);
            if (iou > best) { best = iou; bn = n; }
        }
        int mycell = (cj*WW + ci)*NA + bn;   // produced under full exec

        // duplicate-target resolution: later t wins for the same cell.
        // Only lanes 0..TT-1 are read; their mycell is the real per-target value.
        bool dead = false;
        #pragma unroll 10
        for (int t2 = 0; t2 < TT; ++t2) {
            int c2 = __builtin_amdgcn_readlane(mycell, t2);
            dead = dead || (c2 == mycell && t2 > tid);
        }
        float live = (tid < TT && !dead) ? 1.0f : 0.0f;

        int rem = cj*WW + ci;
        const float* op = out + ((size_t)(b*NA + bn) * KK) * HW + rem;
        float o0 = op[0];
        float o1 = op[HW];
        float o2 = op[2*HW];
        float o3 = op[3*HW];
        float o4 = op[4*HW];

        float tx = bx * WW - (float)ci;
        float ty = by * HH - (float)cj;
        float tw = __logf(bw * WW / pri[2*bn]);
        float th = __logf(bh * HH / pri[2*bn+1]);
        if (tw != tw) tw = 0.0f;  // NaN guard (matches reference)
        if (th != th) th = 0.0f;
        float sc = 2.0f - bw * bh;

        float d0 = sc * (tx - o0);
        float d1 = sc * (ty - o1);
        float d2 = sc * (tw - o2);
        float d3 = sc * (th - o3);
        float dob = 5.0f * (1.0f - o4);
        float s = d0*d0 + d1*d1 + d2*d2 + d3*d3 + dob*dob;
        int tc = (int)floorf(cls);
        #pragma unroll
        for (int c = 0; c < NC; ++c) {
            float oc = op[(size_t)(5 + c) * HW];
            float d = ((c == tc) ? 1.0f : 0.0f) - oc;
            s += d * d;
        }

        // recompute this cell's iou-hit with the bitwise-identical chain,
        // subtract the noobj term the main path added for this cell
        float px = ((float)ci + o0) * (1.0f/WW);
        float py = ((float)cj + o1) * (1.0f/HH);
        float pw = pri[2*bn]   * __expf(o2) * (1.0f/WW);
        float ph = pri[2*bn+1] * __expf(o3) * (1.0f/HH);
        float Ax1 = fmaf(-0.5f, pw, px), Ax2 = fmaf(0.5f, pw, px);
        float Ay1 = fmaf(-0.5f, ph, py), Ay2 = fmaf(0.5f, ph, py);
        float Npb = -0.375f * (pw * ph);
        float acc = -1.0f;
        #pragma unroll 10
        for (int t2 = 0; t2 < TT; ++t2) {
            float sx1 = RDLANE(vx1, t2);
            float sx2 = RDLANE(vx2, t2);
            float sy1 = RDLANE(vy1, t2);
            float sy2 = RDLANE(vy2, t2);
            float sna = RDLANE(vna, t2);
            IOU_STEP(Ax1, Ax2, Ay1, Ay2, Npb, acc);
        }
        s -= (acc > 0.0f) ? 0.0f : o4 * o4;
        mysum = s * live;
    }

    // deterministic block reduction: wave shuffle + LDS across 4 waves
    #pragma unroll
    for (int off = 32; off > 0; off >>= 1)
        mysum += __shfl_down(mysum, off, 64);
    __shared__ float swave[4];
    if ((tid & 63) == 0) swave[tid >> 6] = mysum;
    __syncthreads();
    if (tid == 0)
        partial[blockIdx.y * gridDim.x + blockIdx.x] =
            swave[0] + swave[1] + swave[2] + swave[3];
}

__global__ __launch_bounds__(256) void reduce_kernel(
    const float* __restrict__ partial, int n, float* __restrict__ outp)
{
    int tid = threadIdx.x;
    float s = 0.0f;
    for (int i = tid; i < n; i += 256) s += partial[i];
    #pragma unroll
    for (int off = 32; off > 0; off >>= 1)
        s += __shfl_down(s, off, 64);
    __shared__ float swave[4];
    if ((tid & 63) == 0) swave[tid >> 6] = s;
    __syncthreads();
    if (tid == 0) {
        float total = swave[0] + swave[1] + swave[2] + swave[3];
        float r = sqrtf(total);
        outp[0] = r * r;   // mirror reference: sqrt(sum)^2
    }
}

extern "C" void kernel_launch(void* const* d_in, const int* in_sizes, int n_in,
                              void* d_out, int out_size, void* d_ws, size_t ws_size,
                              hipStream_t stream) {
    const float* output = (const float*)d_in[0];
    const float* target = (const float*)d_in[1];
    const float* priors = (const float*)d_in[2];
    float* partial = (float*)d_ws;   // GX*BB floats, fully overwritten each call

    fused_kernel<<<dim3(GX, BB), 256, 0, stream>>>(output, target, priors, partial);
    reduce_kernel<<<1, 256, 0, stream>>>(partial, GX * BB, (float*)d_out);
}